// Round 14
// baseline (72.297 us; speedup 1.0000x reference)
//
#include <hip/hip_runtime.h>
#include <hip/hip_fp16.h>

#define IN_F    512
#define NC      4096
#define OUT_COLS 640
#define MOH_PITCH 72    // half pitch: 144B rows

typedef __attribute__((ext_vector_type(8)))  short bf16x8;
typedef __attribute__((ext_vector_type(16))) float f32x16;

union H2x4  { uint4 u4; __half2 h[4]; };
union FragB { unsigned int u[4]; bf16x8 s; };

static __device__ __forceinline__ unsigned int pack2(float lo, float hi) {
    return (__float_as_uint(lo) >> 16) | (__float_as_uint(hi) & 0xFFFF0000u);
}
static __device__ __forceinline__ __half2 habs2_(__half2 v) {
    unsigned int u = *(unsigned int*)&v & 0x7FFF7FFFu;
    return *(__half2*)&u;
}

// prep (unchanged, R13-verified): ONE coalesced float4 read -> x->out copy + xa pack
// xa[((mt*32+kc)*64 + khalf*32 + row31)*8 + e]
__global__ __launch_bounds__(256) void prep_kernel(
    const float* __restrict__ x, float* __restrict__ out,
    unsigned short* __restrict__ xa)
{
    const int g = blockIdx.x * 256 + threadIdx.x;   // float4 unit, 0..16383
    const int b = g >> 7, c4 = g & 127;
    float4 v = ((const float4*)x)[g];
    *(float4*)(out + b * OUT_COLS + c4 * 4) = v;
    const int slot = ((b >> 5) * 32 + (c4 >> 2)) * 64 + ((c4 >> 1) & 1) * 32 + (b & 31);
    uint2 pv; pv.x = pack2(v.x, v.y); pv.y = pack2(v.z, v.w);
    *(uint2*)(xa + (size_t)slot * 8 + (c4 & 1) * 4) = pv;
}

// Fused, 2 blocks/CU: block (o = bid&127, jq = bid>>7). 8 waves: (mt 0..3, kg 0..1),
// 32x32x16 MFMA over K=256/wave, A from xa (coalesced), B direct from T.
// 2 K-partials reduced via red; phase 2 does j-quarter jq (2 j per thread).
__global__ __launch_bounds__(512, 4) void fused_kernel(
    const unsigned short* __restrict__ xa,
    const float* __restrict__ T,
    float* __restrict__ out)
{
    __shared__ float red[2 * 4096];                         // 32 KB
    __shared__ __align__(16) __half moh[128 * MOH_PITCH];   // 18 KB
    __shared__ float psum[2 * 528];                         // 4.1 KB

    const int tid    = threadIdx.x;
    const int lane   = tid & 63;
    const int w      = tid >> 6;            // wave 0..7
    const int o      = blockIdx.x & 127;    // strip-sharing blocks 128 apart -> same XCD
    const int jq     = blockIdx.x >> 7;     // j-quarter 0..3
    const int mt     = w & 3;               // rows mt*32..+31
    const int kg     = w >> 2;              // K kg*256..+255
    const int col    = lane & 31;
    const int half32 = lane >> 5;

    // ---- Phase 1: per-wave 32x32 MFMA, no LDS, no barriers ----
    f32x16 acc = {0.f,0.f,0.f,0.f,0.f,0.f,0.f,0.f,0.f,0.f,0.f,0.f,0.f,0.f,0.f,0.f};
    const unsigned short* pa = xa + ((size_t)(mt * 32 + kg * 16) * 64 + lane) * 8;
    const float* pb = T + (size_t)(kg * 256 + half32 * 8) * NC + o * 32 + col;
    #pragma unroll
    for (int ch = 0; ch < 16; ++ch) {       // 16 chunks of K=16
        bf16x8 af = *(const bf16x8*)(pa + (size_t)ch * 512);
        const float* tb = pb + (size_t)ch * 16 * NC;
        float b0 = tb[0*NC], b1 = tb[1*NC], b2 = tb[2*NC], b3 = tb[3*NC];
        float b4 = tb[4*NC], b5 = tb[5*NC], b6 = tb[6*NC], b7 = tb[7*NC];
        FragB bf;
        bf.u[0] = pack2(b0, b1); bf.u[1] = pack2(b2, b3);
        bf.u[2] = pack2(b4, b5); bf.u[3] = pack2(b6, b7);
        acc = __builtin_amdgcn_mfma_f32_32x32x16_bf16(af, bf.s, acc, 0, 0, 0);
    }
    // partials -> red. C/D (m74/m101-verified): col=lane&31, row=(r&3)+8*(r>>2)+4*half32
    {
        float* rd = red + kg * 4096 + mt * 1024 + col;
        #pragma unroll
        for (int r = 0; r < 16; ++r) {
            int row = (r & 3) + 8 * (r >> 2) + 4 * half32;
            rd[row * 32] = acc[r];          // 2 lanes/bank -> free
        }
    }
    __syncthreads();                        // barrier 1

    // ---- reduce 2 K-partials -> moh (fp16); red/moh disjoint, no hazard ----
    {
        const int e0 = tid * 4, e1 = 2048 + tid * 4;
        float4 a0 = *(const float4*)&red[e0];
        float4 p0 = *(const float4*)&red[4096 + e0];
        float4 a1 = *(const float4*)&red[e1];
        float4 p1 = *(const float4*)&red[4096 + e1];
        a0.x += p0.x; a0.y += p0.y; a0.z += p0.z; a0.w += p0.w;
        a1.x += p1.x; a1.y += p1.y; a1.z += p1.z; a1.w += p1.w;
        const int m0t = e0 >> 10, r0 = (e0 >> 5) & 31, c0 = e0 & 31;
        const int m1t = e1 >> 10, r1 = (e1 >> 5) & 31, c1 = e1 & 31;
        __half2 l0 = __floats2half2_rn(a0.x, a0.y), h0 = __floats2half2_rn(a0.z, a0.w);
        __half2 l1 = __floats2half2_rn(a1.x, a1.y), h1 = __floats2half2_rn(a1.z, a1.w);
        uint2 w0, w1;
        w0.x = *(unsigned int*)&l0; w0.y = *(unsigned int*)&h0;
        w1.x = *(unsigned int*)&l1; w1.y = *(unsigned int*)&h1;
        *(uint2*)&moh[(m0t * 32 + r0) * MOH_PITCH + c0] = w0;
        *(uint2*)&moh[(m1t * 32 + r1) * MOH_PITCH + c1] = w1;
    }
    __syncthreads();                        // barrier 2

    // ---- Phase 2: j-quarter jq, 2 j per thread (j0, j0+16) ----
    const int jj4 = tid & 15;
    const int isl = tid >> 4;               // 0..31, i-range isl*4..+4
    const int j0  = jq * 32 + jj4;

    __half2 mj0[16], mj1[16];
    #pragma unroll
    for (int k16 = 0; k16 < 4; ++k16) {
        H2x4 a, b;
        a.u4 = *(const uint4*)&moh[j0 * MOH_PITCH + k16 * 8];
        b.u4 = *(const uint4*)&moh[(j0 + 16) * MOH_PITCH + k16 * 8];
        #pragma unroll
        for (int h = 0; h < 4; ++h) { mj0[k16*4+h] = a.h[h]; mj1[k16*4+h] = b.h[h]; }
    }

    float s0 = 0.f, s1 = 0.f;
    #pragma unroll
    for (int ii = 0; ii < 4; ++ii) {
        const int i = isl * 4 + ii;
        __half2 n0 = __float2half2_rn(0.f), n1 = __float2half2_rn(0.f);
        #pragma unroll
        for (int k16 = 0; k16 < 4; ++k16) { // 4-addr/wave broadcast, ~free
            H2x4 mi; mi.u4 = *(const uint4*)&moh[i * MOH_PITCH + k16 * 8];
            #pragma unroll
            for (int h = 0; h < 4; ++h) {
                n0 = __hadd2(n0, habs2_(__hsub2(mj0[k16*4+h], mi.h[h])));
                n1 = __hadd2(n1, habs2_(__hsub2(mj1[k16*4+h], mi.h[h])));
            }
        }
        float2 f0 = __half22float2(n0), f1 = __half22float2(n1);
        s0 += __expf(-(f0.x + f0.y));       // i==j: identical bits -> norm exactly 0
        s1 += __expf(-(f1.x + f1.y));
    }
    psum[jj4 * 33 + isl]       = s0;
    psum[528 + jj4 * 33 + isl] = s1;
    __syncthreads();                        // barrier 3
    if (tid < 32) {
        int jsel = tid >> 4, jj = tid & 15;
        float tot = 0.f;
        #pragma unroll
        for (int u = 0; u < 32; ++u) tot += psum[jsel * 528 + jj * 33 + u];
        out[(jq * 32 + jsel * 16 + jj) * OUT_COLS + IN_F + o] = tot - 1.0f;
    }
}

extern "C" void kernel_launch(void* const* d_in, const int* in_sizes, int n_in,
                              void* d_out, int out_size, void* d_ws, size_t ws_size,
                              hipStream_t stream) {
    const float* x = (const float*)d_in[0];
    const float* T = (const float*)d_in[1];
    float* out = (float*)d_out;
    unsigned short* xa = (unsigned short*)d_ws;     // 128 KB

    prep_kernel<<<64, 256, 0, stream>>>(x, out, xa);
    fused_kernel<<<512, 512, 0, stream>>>(xa, T, out);
}

// Round 15
// 69.362 us; speedup vs baseline: 1.0423x; 1.0423x over previous
//
#include <hip/hip_runtime.h>
#include <hip/hip_fp16.h>

#define IN_F    512
#define NC      4096
#define OUT_COLS 640
#define B_SZ    128
#define MOH_PITCH 72    // half pitch: 144B rows

typedef __attribute__((ext_vector_type(8)))  short bf16x8;
typedef __attribute__((ext_vector_type(16))) float f32x16;

union H2x4  { uint4 u4; __half2 h[4]; };
union FragB { unsigned int u[4]; bf16x8 s; };

static __device__ __forceinline__ unsigned int pack2(float lo, float hi) {
    return (__float_as_uint(lo) >> 16) | (__float_as_uint(hi) & 0xFFFF0000u);
}
static __device__ __forceinline__ __half2 habs2_(__half2 v) {
    unsigned int u = *(unsigned int*)&v & 0x7FFF7FFFu;
    return *(__half2*)&u;
}

// prep (R13-verified): ONE coalesced float4 read -> x->out copy + xa frag pack
// xa[((mt*32+kc)*64 + khalf*32 + row31)*8 + e]
__global__ __launch_bounds__(256) void prep_kernel(
    const float* __restrict__ x, float* __restrict__ out,
    unsigned short* __restrict__ xa)
{
    const int g = blockIdx.x * 256 + threadIdx.x;   // float4 unit, 0..16383
    const int b = g >> 7, c4 = g & 127;
    float4 v = ((const float4*)x)[g];
    *(float4*)(out + b * OUT_COLS + c4 * 4) = v;
    const int slot = ((b >> 5) * 32 + (c4 >> 2)) * 64 + ((c4 >> 1) & 1) * 32 + (b & 31);
    uint2 pv; pv.x = pack2(v.x, v.y); pv.y = pack2(v.z, v.w);
    *(uint2*)(xa + (size_t)slot * 8 + (c4 & 1) * 4) = pv;
}

// Fused (R13 structure, 69.9 us best) + __launch_bounds__(1024, 8):
// caps VGPRs at 64 -> 2 blocks/CU co-residency (LDS 64KBx2=128<=160, waves 32<=32)
// so one block's compute overlaps the other's barrier drains. No other changes.
__global__ __launch_bounds__(1024, 8) void fused_kernel(
    const unsigned short* __restrict__ xa,
    const float* __restrict__ T,
    float* __restrict__ out)
{
    __shared__ __align__(16) char smem[65536];
    float*  red  = (float*)smem;                    // [kg][mt][row][col] fp32, 64 KB
    __half* moh  = (__half*)smem;                   // overlay after barrier 2
    float*  psum = (float*)(smem + 18432);          // after moh (18432 B)

    const int tid    = threadIdx.x;
    const int lane   = tid & 63;
    const int w      = tid >> 6;            // wave 0..15
    const int o      = blockIdx.x & 127;    // jhalf pair 128 apart -> same XCD (L2 share)
    const int jhalf  = blockIdx.x >> 7;
    const int mt     = w & 3;               // rows mt*32..+31
    const int kg     = w >> 2;              // K kg*128..+127
    const int col    = lane & 31;
    const int half32 = lane >> 5;           // 0/1

    // ---- Phase 1: per-wave 32x32 MFMA over K=128, no LDS, no barriers ----
    f32x16 acc = {0.f,0.f,0.f,0.f,0.f,0.f,0.f,0.f,0.f,0.f,0.f,0.f,0.f,0.f,0.f,0.f};
    const unsigned short* pa = xa + ((size_t)(mt * 32 + kg * 8) * 64 + lane) * 8;
    const float* pb = T + (size_t)(kg * 128 + half32 * 8) * NC + o * 32 + col;
    #pragma unroll
    for (int ch = 0; ch < 8; ++ch) {        // 8 chunks of K=16
        bf16x8 af = *(const bf16x8*)(pa + (size_t)ch * 512);
        const float* tb = pb + (size_t)ch * 16 * NC;
        float b0 = tb[0*NC], b1 = tb[1*NC], b2 = tb[2*NC], b3 = tb[3*NC];
        float b4 = tb[4*NC], b5 = tb[5*NC], b6 = tb[6*NC], b7 = tb[7*NC];
        FragB bf;
        bf.u[0] = pack2(b0, b1); bf.u[1] = pack2(b2, b3);
        bf.u[2] = pack2(b4, b5); bf.u[3] = pack2(b6, b7);
        acc = __builtin_amdgcn_mfma_f32_32x32x16_bf16(af, bf.s, acc, 0, 0, 0);
    }
    // partials -> red. C/D (m74/m101-verified): col=lane&31, row=(r&3)+8*(r>>2)+4*half32
    {
        float* rd = red + kg * 4096 + mt * 1024 + col;
        #pragma unroll
        for (int r = 0; r < 16; ++r) {
            int row = (r & 3) + 8 * (r >> 2) + 4 * half32;
            rd[row * 32] = acc[r];          // 2 lanes/bank -> free
        }
    }
    __syncthreads();                        // barrier 1

    // ---- reduce 4 K-partials (reads), then overlay-write moh as fp16 ----
    float4 s;
    {
        const int e = tid * 4;
        s = *(const float4*)&red[e];
        #pragma unroll
        for (int p = 1; p < 4; ++p) {
            float4 v2 = *(const float4*)&red[p * 4096 + e];
            s.x += v2.x; s.y += v2.y; s.z += v2.z; s.w += v2.w;
        }
    }
    __syncthreads();                        // barrier 2: all red reads done
    {
        const int e = tid * 4;
        const int mtt = e >> 10, row = (e >> 5) & 31, c0 = e & 31;
        __half2 lo = __floats2half2_rn(s.x, s.y);
        __half2 hi = __floats2half2_rn(s.z, s.w);
        uint2 w2; w2.x = *(unsigned int*)&lo; w2.y = *(unsigned int*)&hi;
        *(uint2*)&moh[(mtt * 32 + row) * MOH_PITCH + c0] = w2;
    }
    __syncthreads();                        // barrier 3

    // ---- Phase 2: o_b[j][o] = sum_i exp(-L1(m_i,m_j)) - 1 (R12-verified) ----
    const int jj5 = tid & 31;
    const int isl = tid >> 5;               // 0..31, i-range isl*4..+4
    const int j0  = jhalf * 64 + jj5;

    __half2 mj0[16], mj1[16];
    #pragma unroll
    for (int k16 = 0; k16 < 4; ++k16) {
        H2x4 a, b;
        a.u4 = *(const uint4*)&moh[j0 * MOH_PITCH + k16 * 8];
        b.u4 = *(const uint4*)&moh[(j0 + 32) * MOH_PITCH + k16 * 8];
        #pragma unroll
        for (int h = 0; h < 4; ++h) { mj0[k16*4+h] = a.h[h]; mj1[k16*4+h] = b.h[h]; }
    }

    float s0 = 0.f, s1 = 0.f;
    #pragma unroll
    for (int ii = 0; ii < 4; ++ii) {
        const int i = isl * 4 + ii;
        __half2 n0 = __float2half2_rn(0.f), n1 = __float2half2_rn(0.f);
        #pragma unroll
        for (int k16 = 0; k16 < 4; ++k16) {
            H2x4 mi; mi.u4 = *(const uint4*)&moh[i * MOH_PITCH + k16 * 8];
            #pragma unroll
            for (int h = 0; h < 4; ++h) {
                n0 = __hadd2(n0, habs2_(__hsub2(mj0[k16*4+h], mi.h[h])));
                n1 = __hadd2(n1, habs2_(__hsub2(mj1[k16*4+h], mi.h[h])));
            }
        }
        float2 f0 = __half22float2(n0), f1 = __half22float2(n1);
        s0 += __expf(-(f0.x + f0.y));       // i==j: identical bits -> norm exactly 0
        s1 += __expf(-(f1.x + f1.y));
    }
    psum[jj5 * 33 + isl]        = s0;
    psum[1056 + jj5 * 33 + isl] = s1;
    __syncthreads();                        // barrier 4
    if (tid < 64) {
        int jsel = tid >> 5, jj = tid & 31;
        float tot = 0.f;
        #pragma unroll
        for (int u = 0; u < 32; ++u) tot += psum[jsel * 1056 + jj * 33 + u];
        out[(jhalf * 64 + jsel * 32 + jj) * OUT_COLS + IN_F + o] = tot - 1.0f;
    }
}

extern "C" void kernel_launch(void* const* d_in, const int* in_sizes, int n_in,
                              void* d_out, int out_size, void* d_ws, size_t ws_size,
                              hipStream_t stream) {
    const float* x = (const float*)d_in[0];
    const float* T = (const float*)d_in[1];
    float* out = (float*)d_out;
    unsigned short* xa = (unsigned short*)d_ws;     // 128 KB

    prep_kernel<<<64, 256, 0, stream>>>(x, out, xa);
    fused_kernel<<<256, 1024, 0, stream>>>(xa, T, out);
}